// Round 9
// baseline (1063.197 us; speedup 1.0000x reference)
//
#include <hip/hip_runtime.h>
#include <hip/hip_bf16.h>

typedef __hip_bfloat16 bf16;
typedef __attribute__((ext_vector_type(8))) short short8;
typedef __attribute__((ext_vector_type(4))) short short4v;
typedef __attribute__((ext_vector_type(4))) float floatx4;

__device__ __forceinline__ floatx4 mfma16(short8 a, short8 b, floatx4 c) {
  return __builtin_amdgcn_mfma_f32_16x16x32_bf16(a, b, c, 0, 0, 0);
}

__device__ __forceinline__ float wave_sum(float v) {
#pragma unroll
  for (int off = 1; off < 64; off <<= 1) v += __shfl_xor(v, off);
  return v;
}

// swizzled LDS fragment read: row stride 384B, XOR bits[6:4] with row&7
__device__ __forceinline__ short8 lds_frag(const char* base, int row, int kb) {
  return *(const short8*)(base + row * 384 + (kb ^ ((row & 7) << 4)));
}
// same, row stride 128B
__device__ __forceinline__ short8 lds_frag128(const char* base, int row, int kb) {
  return *(const short8*)(base + row * 128 + (kb ^ ((row & 7) << 4)));
}

// ---------------------------------------------------------------------------
// Weight transpose + bf16 cast: w (K x N) fp32 -> wt (N x K) bf16
// ---------------------------------------------------------------------------
__global__ __launch_bounds__(256) void k_wt(const float* __restrict__ w,
                                            bf16* __restrict__ wt, int K, int N) {
  int id = blockIdx.x * 256 + threadIdx.x;
  if (id < K * N) {
    int n = id / K;
    int k = id - n * K;
    wt[id] = __float2bfloat16(w[(long)k * N + n]);
  }
}

// ---------------------------------------------------------------------------
// LayerNorm over C=192. One wave per row. GATHER=true applies cyclic shift
// (-3,-3) + window partition: output row order = (b, wi, wj, ti, tj).
// ---------------------------------------------------------------------------
template <bool GATHER>
__global__ __launch_bounds__(256) void k_ln(const float* __restrict__ xin,
                                            const float* __restrict__ w,
                                            const float* __restrict__ b,
                                            bf16* __restrict__ out) {
  const int lane = threadIdx.x & 63;
  const long row = (long)blockIdx.x * 4 + (threadIdx.x >> 6);
  long srow;
  if (GATHER) {
    int win = (int)(row / 49);
    int token = (int)(row - (long)win * 49);
    int bimg = win >> 6, wi = (win & 63) >> 3, wj = win & 7;
    int ti = token / 7, tj = token - ti * 7;
    int h = wi * 7 + ti + 3; if (h >= 56) h -= 56;
    int ww = wj * 7 + tj + 3; if (ww >= 56) ww -= 56;
    srow = (long)bimg * 3136 + h * 56 + ww;
  } else {
    srow = row;
  }
  const float* src = xin + srow * 192;
  float v0 = src[lane], v1 = src[lane + 64], v2 = src[lane + 128];
  float mu = wave_sum(v0 + v1 + v2) * (1.f / 192.f);
  float d0 = v0 - mu, d1 = v1 - mu, d2 = v2 - mu;
  float var = wave_sum(d0 * d0 + d1 * d1 + d2 * d2) * (1.f / 192.f);
  float rs = rsqrtf(var + 1e-5f);
  bf16* dst = out + row * 192;
  dst[lane]       = __float2bfloat16(d0 * rs * w[lane] + b[lane]);
  dst[lane + 64]  = __float2bfloat16(d1 * rs * w[lane + 64] + b[lane + 64]);
  dst[lane + 128] = __float2bfloat16(d2 * rs * w[lane + 128] + b[lane + 128]);
}

// ---------------------------------------------------------------------------
// Fused windowed attention v3: one block per window, 768 threads (12 waves),
// WAVE-PAIR-PER-HEAD: waves (2h,2h+1) split head h by token band (0-31/32-63).
// Same LDS as v2 (113.7 KB, 1 block/CU) but 12 resident waves (3/SIMD) for
// 2x the latency hiding. 4 barriers:
//   B1 As staged -> QKV gemm (reads As, writes Q/K/V own band) -> B2 QKV
//   visible -> S (reads own Q rows, ALL K rows) + softmax -> B3 QK reads
//   done -> P overlay write (own rows) -> PV (own P rows, all V) ->
//   O -> Os (=As) -> B4 -> proj (12 waves x 16 cols) + residual + scatter.
// ---------------------------------------------------------------------------
__global__ __launch_bounds__(768, 3) void k_swin(const bf16* __restrict__ xw,
                                                 const bf16* __restrict__ wq,
                                                 const float* __restrict__ qkvb,
                                                 const float* __restrict__ rpb,
                                                 const bf16* __restrict__ wp,
                                                 const float* __restrict__ projb,
                                                 const float* __restrict__ xres,
                                                 float* __restrict__ outf) {
  __shared__ __align__(16) char As[64 * 384];      // x window; later Os
  __shared__ __align__(16) bf16 HeadMem[6][7424];  // per head: Q[0,2560) K[2560,5120) V[5120,7424); P overlays [0,4608)
  const int t = threadIdx.x, lane = t & 63, wid = t >> 6;
  const int head = wid >> 1, half = wid & 1;
  const int lanelo = lane & 15, quad = lane >> 4;
  const int w = blockIdx.x;
  const long rowbase = (long)w * 49;
  const int r0 = half * 32;  // this wave's token band
  bf16* Qs = HeadMem[head];
  bf16* Ks = Qs + 2560;
  bf16* Vt = Qs + 5120;      // [d][token], stride 72
  bf16* Ps = Qs;             // overlays Q/K after S is consumed

  // ---- stage x window (49 rows, zero-pad to 64), swizzled ----
  {
    const char* src = (const char*)(xw + rowbase * 192);
#pragma unroll
    for (int i = 0; i < 2; i++) {
      int c = i * 768 + t;
      int r = c / 24, j = c - r * 24;
      uint4 v;
      if (r < 49) v = *(const uint4*)(src + (long)r * 384 + j * 16);
      else { v.x = 0u; v.y = 0u; v.z = 0u; v.w = 0u; }
      *(uint4*)(As + r * 384 + ((j * 16) ^ ((r & 7) << 4))) = v;
    }
  }

  // ---- per-lane key-column tables (head-independent) ----
  const int w_in = w & 63, wiw = w_in >> 3, wjw = w_in & 7;
  int cTi[4], cTj[4], cLab[4];
  bool cval[4];
#pragma unroll
  for (int ni = 0; ni < 4; ni++) {
    int j = ni * 16 + lanelo;
    cval[ni] = (j < 49);
    if (j > 48) j = 48;
    int ti = j / 7, tj = j - ti * 7;
    int rr = wiw * 7 + ti, cc = wjw * 7 + tj;
    cTi[ni] = ti; cTj[ni] = tj;
    cLab[ni] = ((rr < 49) ? 0 : (rr < 53 ? 1 : 2)) * 3 +
               ((cc < 49) ? 0 : (cc < 53 ? 1 : 2));
  }
  __syncthreads();  // B1: As ready

  const float scale = 0.17677669529663687f;  // 1/sqrt(32)

  // ---- QKV GEMM: own 32 rows x 96 cols (Q|K|V of this head), K=192 ----
  {
    floatx4 aq[2][6];
#pragma unroll
    for (int mi = 0; mi < 2; mi++)
#pragma unroll
      for (int ni = 0; ni < 6; ni++) aq[mi][ni] = (floatx4){0.f, 0.f, 0.f, 0.f};
#pragma unroll
    for (int kk = 0; kk < 6; kk++) {
      const int kb = kk * 64 + quad * 16;
      short8 af[2];
#pragma unroll
      for (int mi = 0; mi < 2; mi++)
        af[mi] = lds_frag(As, r0 + mi * 16 + lanelo, kb);
#pragma unroll
      for (int ni = 0; ni < 6; ni++) {
        const int wrow = (ni >> 1) * 192 + head * 32 + (ni & 1) * 16 + lanelo;
        short8 bf = *(const short8*)((const char*)wq + (long)wrow * 384 + kb);
#pragma unroll
        for (int mi = 0; mi < 2; mi++) aq[mi][ni] = mfma16(af[mi], bf, aq[mi][ni]);
      }
    }
    // epilogue: Q,K row-major [token][d] stride 40; V transposed [d][token]
#pragma unroll
    for (int ni = 0; ni < 6; ni++) {
      const int p = ni >> 1;
      const int d = (ni & 1) * 16 + lanelo;
      const float bb = qkvb[p * 192 + head * 32 + d];
      if (p < 2) {
        bf16* dst = (p == 0) ? Qs : Ks;
#pragma unroll
        for (int mi = 0; mi < 2; mi++)
#pragma unroll
          for (int reg = 0; reg < 4; reg++) {
            int tok = r0 + mi * 16 + quad * 4 + reg;
            dst[tok * 40 + d] = __float2bfloat16(aq[mi][ni][reg] + bb);
          }
      } else {
#pragma unroll
        for (int mi = 0; mi < 2; mi++) {
          union { short4v s; bf16 hh[4]; } pv;
#pragma unroll
          for (int reg = 0; reg < 4; reg++)
            pv.hh[reg] = __float2bfloat16(aq[mi][ni][reg] + bb);
          *(short4v*)(&Vt[d * 72 + r0 + mi * 16 + quad * 4]) = pv.s;
        }
      }
    }
  }
  __syncthreads();  // B2: Q/K/V of both halves visible

  // ---- S = Q K^T (own 32 rows x all 64 keys) + softmax ----
  float rinv[8];
  floatx4 aS[2][4];
  {
#pragma unroll
    for (int mi = 0; mi < 2; mi++) {
      short8 aqf = *(const short8*)(&Qs[(r0 + mi * 16 + lanelo) * 40 + quad * 8]);
#pragma unroll
      for (int ni = 0; ni < 4; ni++) {
        short8 bk = *(const short8*)(&Ks[(ni * 16 + lanelo) * 40 + quad * 8]);
        aS[mi][ni] = mfma16(aqf, bk, (floatx4){0.f, 0.f, 0.f, 0.f});
      }
    }
#pragma unroll
    for (int mi = 0; mi < 2; mi++) {
#pragma unroll
      for (int reg = 0; reg < 4; reg++) {
        int i = r0 + mi * 16 + quad * 4 + reg;
        if (i > 48) i = 48;
        int ti = i / 7, tj = i - ti * 7;
        int rr = wiw * 7 + ti, cc = wjw * 7 + tj;
        int rlab = ((rr < 49) ? 0 : (rr < 53 ? 1 : 2)) * 3 +
                   ((cc < 49) ? 0 : (cc < 53 ? 1 : 2));
        float sv[4];
        float mx = -1e30f;
#pragma unroll
        for (int ni = 0; ni < 4; ni++) {
          float s;
          if (cval[ni]) {
            int ridx = (ti - cTi[ni] + 6) * 13 + (tj - cTj[ni] + 6);
            float bb = rpb[ridx * 6 + head];
            if (rlab != cLab[ni]) bb -= 100.f;
            s = aS[mi][ni][reg] * scale + bb;
          } else {
            s = -1e30f;
          }
          sv[ni] = s;
          mx = fmaxf(mx, s);
        }
        mx = fmaxf(mx, __shfl_xor(mx, 1));
        mx = fmaxf(mx, __shfl_xor(mx, 2));
        mx = fmaxf(mx, __shfl_xor(mx, 4));
        mx = fmaxf(mx, __shfl_xor(mx, 8));
        float sum = 0.f;
#pragma unroll
        for (int ni = 0; ni < 4; ni++) {
          float p = __expf(sv[ni] - mx);
          sv[ni] = p;
          sum += p;
        }
        sum += __shfl_xor(sum, 1);
        sum += __shfl_xor(sum, 2);
        sum += __shfl_xor(sum, 4);
        sum += __shfl_xor(sum, 8);
        rinv[mi * 4 + reg] = 1.f / sum;
#pragma unroll
        for (int ni = 0; ni < 4; ni++) aS[mi][ni][reg] = sv[ni];
      }
    }
  }
  __syncthreads();  // B3: all Q/K reads done -> safe to overlay P

  // P -> LDS (own rows; stride 72)
#pragma unroll
  for (int mi = 0; mi < 2; mi++)
#pragma unroll
    for (int ni = 0; ni < 4; ni++)
#pragma unroll
      for (int reg = 0; reg < 4; reg++)
        Ps[(r0 + mi * 16 + quad * 4 + reg) * 72 + ni * 16 + lanelo] =
            __float2bfloat16(aS[mi][ni][reg]);

  // ---- O = P * V : own 32 rows x 32 cols, K=64 (own P rows, all V) ----
  floatx4 aO[2][2];
#pragma unroll
  for (int mi = 0; mi < 2; mi++)
#pragma unroll
    for (int ni = 0; ni < 2; ni++) aO[mi][ni] = (floatx4){0.f, 0.f, 0.f, 0.f};
#pragma unroll
  for (int ks = 0; ks < 2; ks++) {
#pragma unroll
    for (int mi = 0; mi < 2; mi++) {
      short8 ap = *(const short8*)(&Ps[(r0 + mi * 16 + lanelo) * 72 + ks * 32 + quad * 8]);
#pragma unroll
      for (int ni = 0; ni < 2; ni++) {
        short8 bv = *(const short8*)(&Vt[(ni * 16 + lanelo) * 72 + ks * 32 + quad * 8]);
        aO[mi][ni] = mfma16(ap, bv, aO[mi][ni]);
      }
    }
  }

  // ---- write O band (own rows, cols head*32..+31) into Os (=As) ----
#pragma unroll
  for (int mi = 0; mi < 2; mi++)
#pragma unroll
    for (int ni = 0; ni < 2; ni++)
#pragma unroll
      for (int reg = 0; reg < 4; reg++) {
        int tok = r0 + mi * 16 + quad * 4 + reg;
        int cb = 2 * (head * 32 + ni * 16 + lanelo);
        *(bf16*)(As + tok * 384 + (cb ^ ((tok & 7) << 4))) =
            __float2bfloat16(aO[mi][ni][reg] * rinv[mi * 4 + reg]);
      }
  __syncthreads();  // B4: Os complete

  // ---- proj: each wave does out cols [wid*16, +16), all 64 rows, K=192 ----
  floatx4 accp[4];
#pragma unroll
  for (int mi = 0; mi < 4; mi++) accp[mi] = (floatx4){0.f, 0.f, 0.f, 0.f};
#pragma unroll
  for (int kk = 0; kk < 6; kk++) {
    const int kb = kk * 64 + quad * 16;
    short8 bf = *(const short8*)((const char*)wp +
                                 (long)(wid * 16 + lanelo) * 384 + kb);
#pragma unroll
    for (int mi = 0; mi < 4; mi++) {
      short8 af = lds_frag(As, mi * 16 + lanelo, kb);
      accp[mi] = mfma16(af, bf, accp[mi]);
    }
  }
  // epilogue: + bias + residual, window-reverse scatter (fp32)
#pragma unroll
  for (int mi = 0; mi < 4; mi++)
#pragma unroll
    for (int reg = 0; reg < 4; reg++) {
      const int tok = mi * 16 + quad * 4 + reg;
      if (tok < 49) {
        int ti = tok / 7, tj = tok - ti * 7;
        int hh = wiw * 7 + ti + 3; if (hh >= 56) hh -= 56;
        int ww2 = wjw * 7 + tj + 3; if (ww2 >= 56) ww2 -= 56;
        const long orow = (long)(w >> 6) * 3136 + hh * 56 + ww2;
        const int c = wid * 16 + lanelo;
        outf[orow * 192 + c] = accp[mi][reg] + projb[c] + xres[orow * 192 + c];
      }
    }
}

// ---------------------------------------------------------------------------
// Fused LN2 + fc1 + GELU + fc2 + residual, in-place on the fp32 tensor.
// 64 rows/block, 256 threads, 3136 blocks, 4 blocks/CU (LDS 40KB).
// Direct-global weight fragments; Hs double-buffered; 1 barrier/chunk.
// ---------------------------------------------------------------------------
__global__ __launch_bounds__(256, 4) void k_mlp(float* xres,
                                                const float* __restrict__ lw,
                                                const float* __restrict__ lb,
                                                const bf16* __restrict__ w1t,
                                                const float* __restrict__ b1,
                                                const bf16* __restrict__ w2t,
                                                const float* __restrict__ b2) {
  __shared__ __align__(16) char As[64 * 384];     // LN'd rows, K=192 (swizzled)
  __shared__ __align__(16) char Hs[2][64 * 128];  // gelu(hid) chunk dbuf
  const int t = threadIdx.x, lane = t & 63, wid = t >> 6;
  const int lanelo = lane & 15, quad = lane >> 4;
  const long row0 = (long)blockIdx.x * 64;

  // ---- LN2 -> As (bf16, row-XOR swizzled); 16 rows per wave ----
  for (int i = 0; i < 16; i++) {
    int r = wid * 16 + i;
    const float* src = xres + (row0 + r) * 192;
    float v0 = src[lane], v1 = src[lane + 64], v2 = src[lane + 128];
    float mu = wave_sum(v0 + v1 + v2) * (1.f / 192.f);
    float d0 = v0 - mu, d1 = v1 - mu, d2 = v2 - mu;
    float var = wave_sum(d0 * d0 + d1 * d1 + d2 * d2) * (1.f / 192.f);
    float rs = rsqrtf(var + 1e-5f);
    int sw = (r & 7) << 4;
    *(bf16*)(As + r * 384 + ((2 * lane) ^ sw)) =
        __float2bfloat16(d0 * rs * lw[lane] + lb[lane]);
    *(bf16*)(As + r * 384 + ((128 + 2 * lane) ^ sw)) =
        __float2bfloat16(d1 * rs * lw[lane + 64] + lb[lane + 64]);
    *(bf16*)(As + r * 384 + ((256 + 2 * lane) ^ sw)) =
        __float2bfloat16(d2 * rs * lw[lane + 128] + lb[lane + 128]);
  }

  floatx4 acc2[4][3];
#pragma unroll
  for (int mi = 0; mi < 4; mi++)
#pragma unroll
    for (int ni = 0; ni < 3; ni++) acc2[mi][ni] = (floatx4){0.f, 0.f, 0.f, 0.f};

  __syncthreads();  // As ready

  const int hcol = wid * 16 + lanelo;          // GEMM1 col owned by this lane
  const int ocol0 = wid * 48;                  // GEMM2 col base for this wave

  for (int nc = 0; nc < 12; nc++) {
    // GEMM1: hid chunk cols [nc*64 + wid*16, +16), 64 rows, K=192.
    const char* w1p = (const char*)w1t + (long)(nc * 64 + hcol) * 384;
    floatx4 acc1[4];
#pragma unroll
    for (int mi = 0; mi < 4; mi++) acc1[mi] = (floatx4){0.f, 0.f, 0.f, 0.f};
#pragma unroll
    for (int kk = 0; kk < 6; kk++) {
      const int kb = kk * 64 + quad * 16;
      short8 bf = *(const short8*)(w1p + kb);
#pragma unroll
      for (int mi = 0; mi < 4; mi++) {
        short8 af = lds_frag(As, mi * 16 + lanelo, kb);
        acc1[mi] = mfma16(af, bf, acc1[mi]);
      }
    }

    // bias + exact GELU -> Hs[nc&1] (bf16, swizzled)
    char* H = Hs[nc & 1];
    const float b1v = b1[nc * 64 + hcol];
#pragma unroll
    for (int mi = 0; mi < 4; mi++)
#pragma unroll
      for (int reg = 0; reg < 4; reg++) {
        int r = mi * 16 + quad * 4 + reg;
        float v = acc1[mi][reg] + b1v;
        v = 0.5f * v * (1.f + erff(v * 0.70710678118654752f));
        *(bf16*)(H + r * 128 + ((2 * hcol) ^ ((r & 7) << 4))) =
            __float2bfloat16(v);
      }
    __syncthreads();  // Hs[nc&1] ready; also guards WAR on Hs[(nc-1)&1]

    // GEMM2 partial: out 64x192 += H(64x64) * W2chunk^T, wave tile 64x48.
#pragma unroll
    for (int ks = 0; ks < 2; ks++) {
      const int kb = ks * 64 + quad * 16;
      short8 ha[4];
#pragma unroll
      for (int mi = 0; mi < 4; mi++)
        ha[mi] = lds_frag128(H, mi * 16 + lanelo, kb);
#pragma unroll
      for (int ni = 0; ni < 3; ni++) {
        short8 bv = *(const short8*)((const char*)w2t +
                                     (long)(ocol0 + ni * 16 + lanelo) * 1536 +
                                     nc * 128 + kb);
#pragma unroll
        for (int mi = 0; mi < 4; mi++)
          acc2[mi][ni] = mfma16(ha[mi], bv, acc2[mi][ni]);
      }
    }
  }

  // epilogue: + bias2 + residual, fp32 in-place
#pragma unroll
  for (int mi = 0; mi < 4; mi++)
#pragma unroll
    for (int ni = 0; ni < 3; ni++) {
      const int c = ocol0 + ni * 16 + lanelo;
      const float b2v = b2[c];
#pragma unroll
      for (int reg = 0; reg < 4; reg++) {
        const long g = (row0 + mi * 16 + quad * 4 + reg) * 192 + c;
        xres[g] = acc2[mi][ni][reg] + b2v + xres[g];
      }
    }
}

// ---------------------------------------------------------------------------
extern "C" void kernel_launch(void* const* d_in, const int* in_sizes, int n_in,
                              void* d_out, int out_size, void* d_ws, size_t ws_size,
                              hipStream_t stream) {
  const float* x     = (const float*)d_in[0];
  const float* n1w   = (const float*)d_in[1];
  const float* n1b   = (const float*)d_in[2];
  const float* qkvw  = (const float*)d_in[3];
  const float* qkvb  = (const float*)d_in[4];
  const float* rpb   = (const float*)d_in[5];
  const float* projw = (const float*)d_in[6];
  const float* projb = (const float*)d_in[7];
  const float* n2w   = (const float*)d_in[8];
  const float* n2b   = (const float*)d_in[9];
  const float* fc1w  = (const float*)d_in[10];
  const float* fc1b  = (const float*)d_in[11];
  const float* fc2w  = (const float*)d_in[12];
  const float* fc2b  = (const float*)d_in[13];
  float* outf = (float*)d_out;  // residual buffer, then final output

  // workspace layout:
  //   B0 [0,        77070336)  xw bf16 (200704x192)
  //   W  [154140672, ...)      bf16 weights (~0.9 MB)
  char* ws = (char*)d_ws;
  bf16* xw      = (bf16*)(ws + 0);
  bf16* wt_qkv  = (bf16*)(ws + 154140672LL);                  // 576x192
  bf16* wt_proj = (bf16*)(ws + 154140672LL + 221184LL);       // 192x192
  bf16* wt_fc1  = (bf16*)(ws + 154140672LL + 294912LL);       // 768x192
  bf16* wt_fc2  = (bf16*)(ws + 154140672LL + 589824LL);       // 192x768

  // transpose + cast weights to bf16 (N x K)
  k_wt<<<dim3((192 * 576 + 255) / 256), 256, 0, stream>>>(qkvw, wt_qkv, 192, 576);
  k_wt<<<dim3((192 * 192 + 255) / 256), 256, 0, stream>>>(projw, wt_proj, 192, 192);
  k_wt<<<dim3((192 * 768 + 255) / 256), 256, 0, stream>>>(fc1w, wt_fc1, 192, 768);
  k_wt<<<dim3((768 * 192 + 255) / 256), 256, 0, stream>>>(fc2w, wt_fc2, 768, 192);

  // LN1 + shift + window partition -> xw (window-order rows, full tensor)
  k_ln<true><<<dim3(50176), 256, 0, stream>>>(x, n1w, n1b, xw);

  // fused attention: qkv + windowed MHA + proj + residual, one block/window
  k_swin<<<dim3(4096), 768, 0, stream>>>(xw, wt_qkv, qkvb, rpb, wt_proj, projb,
                                         x, outf);

  // fused LN2 + MLP + residual, in-place on d_out (64 rows per block)
  k_mlp<<<dim3(3136), 256, 0, stream>>>(outf, n2w, n2b, wt_fc1, fc1b,
                                        wt_fc2, fc2b);
}

// Round 10
// 993.082 us; speedup vs baseline: 1.0706x; 1.0706x over previous
//
#include <hip/hip_runtime.h>
#include <hip/hip_bf16.h>

typedef __hip_bfloat16 bf16;
typedef __attribute__((ext_vector_type(8))) short short8;
typedef __attribute__((ext_vector_type(4))) short short4v;
typedef __attribute__((ext_vector_type(4))) float floatx4;

__device__ __forceinline__ floatx4 mfma16(short8 a, short8 b, floatx4 c) {
  return __builtin_amdgcn_mfma_f32_16x16x32_bf16(a, b, c, 0, 0, 0);
}

__device__ __forceinline__ float wave_sum(float v) {
#pragma unroll
  for (int off = 1; off < 64; off <<= 1) v += __shfl_xor(v, off);
  return v;
}

// async global -> LDS, 16 bytes per lane
__device__ __forceinline__ void gload16(const void* g, void* l) {
  __builtin_amdgcn_global_load_lds(
      (const __attribute__((address_space(1))) unsigned int*)g,
      (__attribute__((address_space(3))) unsigned int*)l, 16, 0, 0);
}

// swizzled LDS fragment read: row stride 384B, XOR bits[6:4] with row&7
__device__ __forceinline__ short8 lds_frag(const char* base, int row, int kb) {
  return *(const short8*)(base + row * 384 + (kb ^ ((row & 7) << 4)));
}
// same, row stride 128B
__device__ __forceinline__ short8 lds_frag128(const char* base, int row, int kb) {
  return *(const short8*)(base + row * 128 + (kb ^ ((row & 7) << 4)));
}

// ---------------------------------------------------------------------------
// Weight transpose + bf16 cast: w (K x N) fp32 -> wt (N x K) bf16
// ---------------------------------------------------------------------------
__global__ __launch_bounds__(256) void k_wt(const float* __restrict__ w,
                                            bf16* __restrict__ wt, int K, int N) {
  int id = blockIdx.x * 256 + threadIdx.x;
  if (id < K * N) {
    int n = id / K;
    int k = id - n * K;
    wt[id] = __float2bfloat16(w[(long)k * N + n]);
  }
}

// ---------------------------------------------------------------------------
// LayerNorm over C=192. One wave per row. GATHER=true applies cyclic shift
// (-3,-3) + window partition: output row order = (b, wi, wj, ti, tj).
// ---------------------------------------------------------------------------
template <bool GATHER>
__global__ __launch_bounds__(256) void k_ln(const float* __restrict__ xin,
                                            const float* __restrict__ w,
                                            const float* __restrict__ b,
                                            bf16* __restrict__ out) {
  const int lane = threadIdx.x & 63;
  const long row = (long)blockIdx.x * 4 + (threadIdx.x >> 6);
  long srow;
  if (GATHER) {
    int win = (int)(row / 49);
    int token = (int)(row - (long)win * 49);
    int bimg = win >> 6, wi = (win & 63) >> 3, wj = win & 7;
    int ti = token / 7, tj = token - ti * 7;
    int h = wi * 7 + ti + 3; if (h >= 56) h -= 56;
    int ww = wj * 7 + tj + 3; if (ww >= 56) ww -= 56;
    srow = (long)bimg * 3136 + h * 56 + ww;
  } else {
    srow = row;
  }
  const float* src = xin + srow * 192;
  float v0 = src[lane], v1 = src[lane + 64], v2 = src[lane + 128];
  float mu = wave_sum(v0 + v1 + v2) * (1.f / 192.f);
  float d0 = v0 - mu, d1 = v1 - mu, d2 = v2 - mu;
  float var = wave_sum(d0 * d0 + d1 * d1 + d2 * d2) * (1.f / 192.f);
  float rs = rsqrtf(var + 1e-5f);
  bf16* dst = out + row * 192;
  dst[lane]       = __float2bfloat16(d0 * rs * w[lane] + b[lane]);
  dst[lane + 64]  = __float2bfloat16(d1 * rs * w[lane + 64] + b[lane + 64]);
  dst[lane + 128] = __float2bfloat16(d2 * rs * w[lane + 128] + b[lane + 128]);
}

// ---------------------------------------------------------------------------
// GEMM: C = A (M x K, bf16 rm) * Bt^T (Bt is N x K bf16) + bias
// 64x64 block tile, 4 waves of 32x32, MFMA 16x16x32 bf16.
// EPI 2: window-reverse scatter + shortcut add, fp32   [proj -> d_out]
// ---------------------------------------------------------------------------
template <int EPI>
__global__ __launch_bounds__(256, 3) void k_gemm(const bf16* __restrict__ A,
                                                 const bf16* __restrict__ Bt,
                                                 const float* __restrict__ bias,
                                                 bf16* __restrict__ Cbf,
                                                 float* __restrict__ Cfp,
                                                 const float* __restrict__ res,
                                                 int Ncols, int K, long row0) {
  __shared__ __align__(16) char As[64 * 384];  // 24576 B: 64 rows x 192 bf16
  __shared__ __align__(16) char Bs[64 * 384];
  const int t = threadIdx.x;
  const int lane = t & 63, wid = t >> 6;
  const int lanelo = lane & 15, quad = lane >> 4;
  const long m0 = (long)blockIdx.x * 64;
  const int n0 = blockIdx.y * 64;
  const int wm = (wid >> 1) * 32, wn = (wid & 1) * 32;

  floatx4 acc[2][2];
#pragma unroll
  for (int i = 0; i < 2; i++)
#pragma unroll
    for (int j = 0; j < 2; j++) acc[i][j] = (floatx4){0.f, 0.f, 0.f, 0.f};

  const char* Ab = (const char*)(A + m0 * (long)K);
  const char* Bb = (const char*)(Bt + (long)n0 * K);
  const int ldab = 2 * K;  // bytes per source row

  for (int k0b = 0; k0b < 2 * K; k0b += 384) {
    __syncthreads();
#pragma unroll
    for (int i = 0; i < 6; i++) {
      int c = i * 256 + t;          // chunk index
      int r = c / 24;               // row in tile (24 chunks per 384B row)
      int j = c - r * 24;
      int be = (j * 16) ^ ((r & 7) << 4);
      gload16(Ab + (long)r * ldab + k0b + be, As + c * 16);
      gload16(Bb + (long)r * ldab + k0b + be, Bs + c * 16);
    }
    __syncthreads();  // drains vmcnt(0) -> panels resident

#pragma unroll
    for (int kk = 0; kk < 6; kk++) {
      const int kb = kk * 64 + quad * 16;
      short8 a0 = lds_frag(As, wm + lanelo, kb);
      short8 a1 = lds_frag(As, wm + 16 + lanelo, kb);
      short8 b0 = lds_frag(Bs, wn + lanelo, kb);
      short8 b1 = lds_frag(Bs, wn + 16 + lanelo, kb);
      acc[0][0] = mfma16(a0, b0, acc[0][0]);
      acc[0][1] = mfma16(a0, b1, acc[0][1]);
      acc[1][0] = mfma16(a1, b0, acc[1][0]);
      acc[1][1] = mfma16(a1, b1, acc[1][1]);
    }
  }

#pragma unroll
  for (int mi = 0; mi < 2; mi++) {
#pragma unroll
    for (int reg = 0; reg < 4; reg++) {
      const long r = m0 + wm + mi * 16 + quad * 4 + reg;
      long orow = r;
      if (EPI == 2) {
        const long rg = row0 + r;
        int win = (int)(rg / 49);
        int token = (int)(rg - (long)win * 49);
        int bimg = win >> 6, wi = (win & 63) >> 3, wj = win & 7;
        int ti = token / 7, tj = token - ti * 7;
        int h = wi * 7 + ti + 3; if (h >= 56) h -= 56;
        int ww = wj * 7 + tj + 3; if (ww >= 56) ww -= 56;
        orow = (long)bimg * 3136 + h * 56 + ww;
      }
#pragma unroll
      for (int ni = 0; ni < 2; ni++) {
        const int c = n0 + wn + ni * 16 + lanelo;
        float v = acc[mi][ni][reg] + bias[c];
        if (EPI == 0) {
          Cbf[r * Ncols + c] = __float2bfloat16(v);
        } else if (EPI == 1) {
          v = 0.5f * v * (1.f + erff(v * 0.70710678118654752f));
          Cbf[r * Ncols + c] = __float2bfloat16(v);
        } else if (EPI == 2) {
          Cfp[orow * 192 + c] = v + res[orow * 192 + c];
        } else {
          Cfp[r * 192 + c] = v + res[r * 192 + c];
        }
      }
    }
  }
}

// ---------------------------------------------------------------------------
// QKV + windowed attention, one WAVE per (window, head), ZERO barriers.
// 4 waves/block, wave-private LDS (Q/K stride 40, Vt [d][tok] stride 72,
// P overlays Q/K). QKV A-fragments read DIRECTLY from global xw (L3-resident,
// 6x reuse across heads); B-fragments from L2 weights. Output O (32 cols of
// this head) written to attC. Pad rows/cols handled exactly as before
// (cval mask, i<49 store guard; pad-row garbage never escapes).
// LDS: 4 x 14848 B = 59392 -> 2 blocks/CU, 8 independent waves/CU.
// ---------------------------------------------------------------------------
__global__ __launch_bounds__(256, 2) void k_attn2(const bf16* __restrict__ xw,
                                                  const bf16* __restrict__ wq,
                                                  const float* __restrict__ qkvb,
                                                  const float* __restrict__ rpb,
                                                  bf16* __restrict__ attC) {
  __shared__ __align__(16) bf16 smem[4 * 7424];
  const int t = threadIdx.x, lane = t & 63, wid = t >> 6;
  const int lanelo = lane & 15, quad = lane >> 4;
  const int unit = blockIdx.x * 4 + wid;
  const int win = unit / 6, head = unit - win * 6;
  bf16* Qs = smem + wid * 7424;  // 64 rows, stride 40
  bf16* Ks = Qs + 2560;          // 64 rows, stride 40
  bf16* Vt = Qs + 5120;          // 32 rows (d), stride 72, cols = token
  bf16* Ps = Qs;                 // 64 rows, stride 72 (overlays Q/K)
  const long rowbase = (long)win * 49;

  // ---- per-lane key-column tables ----
  const int w_in = win & 63, wiw = w_in >> 3, wjw = w_in & 7;
  int cTi[4], cTj[4], cLab[4];
  bool cval[4];
#pragma unroll
  for (int ni = 0; ni < 4; ni++) {
    int j = ni * 16 + lanelo;
    cval[ni] = (j < 49);
    if (j > 48) j = 48;
    int ti = j / 7, tj = j - ti * 7;
    int rr = wiw * 7 + ti, cc = wjw * 7 + tj;
    cTi[ni] = ti; cTj[ni] = tj;
    cLab[ni] = ((rr < 49) ? 0 : (rr < 53 ? 1 : 2)) * 3 +
               ((cc < 49) ? 0 : (cc < 53 ? 1 : 2));
  }

  const float scale = 0.17677669529663687f;  // 1/sqrt(32)

  // ---- QKV GEMM for this head: 64 rows x 96 cols (Q|K|V), K=192 ----
  {
    floatx4 aq[4][6];
#pragma unroll
    for (int mi = 0; mi < 4; mi++)
#pragma unroll
      for (int ni = 0; ni < 6; ni++) aq[mi][ni] = (floatx4){0.f, 0.f, 0.f, 0.f};
#pragma unroll
    for (int kk = 0; kk < 6; kk++) {
      const int kb = kk * 64 + quad * 16;
      short8 af[4];
#pragma unroll
      for (int mi = 0; mi < 4; mi++)
        af[mi] = *(const short8*)((const char*)xw +
                                  (rowbase + mi * 16 + lanelo) * 384 + kb);
#pragma unroll
      for (int ni = 0; ni < 6; ni++) {
        const int wrow = (ni >> 1) * 192 + head * 32 + (ni & 1) * 16 + lanelo;
        short8 bf = *(const short8*)((const char*)wq + (long)wrow * 384 + kb);
#pragma unroll
        for (int mi = 0; mi < 4; mi++) aq[mi][ni] = mfma16(af[mi], bf, aq[mi][ni]);
      }
    }
    // epilogue: Q,K row-major [token][d] stride 40; V transposed [d][token]
#pragma unroll
    for (int ni = 0; ni < 6; ni++) {
      const int p = ni >> 1;
      const int d = (ni & 1) * 16 + lanelo;
      const float bb = qkvb[p * 192 + head * 32 + d];
      if (p < 2) {
        bf16* dst = (p == 0) ? Qs : Ks;
#pragma unroll
        for (int mi = 0; mi < 4; mi++)
#pragma unroll
          for (int reg = 0; reg < 4; reg++) {
            int tok = mi * 16 + quad * 4 + reg;
            dst[tok * 40 + d] = __float2bfloat16(aq[mi][ni][reg] + bb);
          }
      } else {
#pragma unroll
        for (int mi = 0; mi < 4; mi++) {
          union { short4v s; bf16 hh[4]; } pv;
#pragma unroll
          for (int reg = 0; reg < 4; reg++)
            pv.hh[reg] = __float2bfloat16(aq[mi][ni][reg] + bb);
          *(short4v*)(&Vt[d * 72 + mi * 16 + quad * 4]) = pv.s;
        }
      }
    }
  }
  // wave-private LDS: in-wave lgkmcnt ordering suffices, no barrier

  // ---- S = Q K^T : 64x64 + softmax ----
  float rinv[16];
  {
    floatx4 aS[4][4];
#pragma unroll
    for (int mi = 0; mi < 4; mi++) {
      short8 aqf = *(const short8*)(&Qs[(mi * 16 + lanelo) * 40 + quad * 8]);
#pragma unroll
      for (int ni = 0; ni < 4; ni++) {
        short8 bk = *(const short8*)(&Ks[(ni * 16 + lanelo) * 40 + quad * 8]);
        aS[mi][ni] = mfma16(aqf, bk, (floatx4){0.f, 0.f, 0.f, 0.f});
      }
    }
#pragma unroll
    for (int mi = 0; mi < 4; mi++) {
#pragma unroll
      for (int reg = 0; reg < 4; reg++) {
        int i = mi * 16 + quad * 4 + reg;
        if (i > 48) i = 48;
        int ti = i / 7, tj = i - ti * 7;
        int rr = wiw * 7 + ti, cc = wjw * 7 + tj;
        int rlab = ((rr < 49) ? 0 : (rr < 53 ? 1 : 2)) * 3 +
                   ((cc < 49) ? 0 : (cc < 53 ? 1 : 2));
        float sv[4];
        float mx = -1e30f;
#pragma unroll
        for (int ni = 0; ni < 4; ni++) {
          float s;
          if (cval[ni]) {
            int ridx = (ti - cTi[ni] + 6) * 13 + (tj - cTj[ni] + 6);
            float bb = rpb[ridx * 6 + head];
            if (rlab != cLab[ni]) bb -= 100.f;
            s = aS[mi][ni][reg] * scale + bb;
          } else {
            s = -1e30f;
          }
          sv[ni] = s;
          mx = fmaxf(mx, s);
        }
        mx = fmaxf(mx, __shfl_xor(mx, 1));
        mx = fmaxf(mx, __shfl_xor(mx, 2));
        mx = fmaxf(mx, __shfl_xor(mx, 4));
        mx = fmaxf(mx, __shfl_xor(mx, 8));
        float sum = 0.f;
#pragma unroll
        for (int ni = 0; ni < 4; ni++) {
          float p = __expf(sv[ni] - mx);
          sv[ni] = p;
          sum += p;
        }
        sum += __shfl_xor(sum, 1);
        sum += __shfl_xor(sum, 2);
        sum += __shfl_xor(sum, 4);
        sum += __shfl_xor(sum, 8);
        rinv[mi * 4 + reg] = 1.f / sum;
#pragma unroll
        for (int ni = 0; ni < 4; ni++) aS[mi][ni][reg] = sv[ni];
      }
    }
    // P -> LDS (overlays Q/K; same-wave DS ops are ordered)
#pragma unroll
    for (int mi = 0; mi < 4; mi++)
#pragma unroll
      for (int ni = 0; ni < 4; ni++)
#pragma unroll
        for (int reg = 0; reg < 4; reg++)
          Ps[(mi * 16 + quad * 4 + reg) * 72 + ni * 16 + lanelo] =
              __float2bfloat16(aS[mi][ni][reg]);
  }

  // ---- O = P * V : 64x32, K=64 ----
  floatx4 aO[4][2];
#pragma unroll
  for (int mi = 0; mi < 4; mi++)
#pragma unroll
    for (int ni = 0; ni < 2; ni++) aO[mi][ni] = (floatx4){0.f, 0.f, 0.f, 0.f};
#pragma unroll
  for (int ks = 0; ks < 2; ks++) {
#pragma unroll
    for (int mi = 0; mi < 4; mi++) {
      short8 ap = *(const short8*)(&Ps[(mi * 16 + lanelo) * 72 + ks * 32 + quad * 8]);
#pragma unroll
      for (int ni = 0; ni < 2; ni++) {
        short8 bv = *(const short8*)(&Vt[(ni * 16 + lanelo) * 72 + ks * 32 + quad * 8]);
        aO[mi][ni] = mfma16(ap, bv, aO[mi][ni]);
      }
    }
  }

  // ---- store O band (this head's 32 cols) to attC ----
#pragma unroll
  for (int mi = 0; mi < 4; mi++)
#pragma unroll
    for (int reg = 0; reg < 4; reg++) {
      int i = mi * 16 + quad * 4 + reg;
      if (i < 49) {
        float rv = rinv[mi * 4 + reg];
#pragma unroll
        for (int ni = 0; ni < 2; ni++) {
          int d = ni * 16 + lanelo;
          attC[(rowbase + i) * 192 + head * 32 + d] =
              __float2bfloat16(aO[mi][ni][reg] * rv);
        }
      }
    }
}

// ---------------------------------------------------------------------------
// Fused LN2 + fc1 + GELU + fc2 + residual, in-place on the fp32 tensor.
// 64 rows/block, 256 threads, 3136 blocks, 4 blocks/CU (LDS 40KB).
// Direct-global weight fragments; Hs double-buffered; 1 barrier/chunk.
// ---------------------------------------------------------------------------
__global__ __launch_bounds__(256, 4) void k_mlp(float* xres,
                                                const float* __restrict__ lw,
                                                const float* __restrict__ lb,
                                                const bf16* __restrict__ w1t,
                                                const float* __restrict__ b1,
                                                const bf16* __restrict__ w2t,
                                                const float* __restrict__ b2) {
  __shared__ __align__(16) char As[64 * 384];     // LN'd rows, K=192 (swizzled)
  __shared__ __align__(16) char Hs[2][64 * 128];  // gelu(hid) chunk dbuf
  const int t = threadIdx.x, lane = t & 63, wid = t >> 6;
  const int lanelo = lane & 15, quad = lane >> 4;
  const long row0 = (long)blockIdx.x * 64;

  // ---- LN2 -> As (bf16, row-XOR swizzled); 16 rows per wave ----
  for (int i = 0; i < 16; i++) {
    int r = wid * 16 + i;
    const float* src = xres + (row0 + r) * 192;
    float v0 = src[lane], v1 = src[lane + 64], v2 = src[lane + 128];
    float mu = wave_sum(v0 + v1 + v2) * (1.f / 192.f);
    float d0 = v0 - mu, d1 = v1 - mu, d2 = v2 - mu;
    float var = wave_sum(d0 * d0 + d1 * d1 + d2 * d2) * (1.f / 192.f);
    float rs = rsqrtf(var + 1e-5f);
    int sw = (r & 7) << 4;
    *(bf16*)(As + r * 384 + ((2 * lane) ^ sw)) =
        __float2bfloat16(d0 * rs * lw[lane] + lb[lane]);
    *(bf16*)(As + r * 384 + ((128 + 2 * lane) ^ sw)) =
        __float2bfloat16(d1 * rs * lw[lane + 64] + lb[lane + 64]);
    *(bf16*)(As + r * 384 + ((256 + 2 * lane) ^ sw)) =
        __float2bfloat16(d2 * rs * lw[lane + 128] + lb[lane + 128]);
  }

  floatx4 acc2[4][3];
#pragma unroll
  for (int mi = 0; mi < 4; mi++)
#pragma unroll
    for (int ni = 0; ni < 3; ni++) acc2[mi][ni] = (floatx4){0.f, 0.f, 0.f, 0.f};

  __syncthreads();  // As ready

  const int hcol = wid * 16 + lanelo;          // GEMM1 col owned by this lane
  const int ocol0 = wid * 48;                  // GEMM2 col base for this wave

  for (int nc = 0; nc < 12; nc++) {
    // GEMM1: hid chunk cols [nc*64 + wid*16, +16), 64 rows, K=192.
    const char* w1p = (const char*)w1t + (long)(nc * 64 + hcol) * 384;
    floatx4 acc1[4];
#pragma unroll
    for (int mi = 0; mi < 4; mi++) acc1[mi] = (floatx4){0.f, 0.f, 0.f, 0.f};
#pragma unroll
    for (int kk = 0; kk < 6; kk++) {
      const int kb = kk * 64 + quad * 16;
      short8 bf = *(const short8*)(w1p + kb);
#pragma unroll
      for (int mi = 0; mi < 4; mi++) {
        short8 af = lds_frag(As, mi * 16 + lanelo, kb);
        acc1[mi] = mfma16(af, bf, acc1[mi]);
      }
    }

    // bias + exact GELU -> Hs[nc&1] (bf16, swizzled)
    char* H = Hs[nc & 1];
    const float b1v = b1[nc * 64 + hcol];
#pragma unroll
    for (int mi = 0; mi < 4; mi++)
#pragma unroll
      for (int reg = 0; reg < 4; reg++) {
        int r = mi * 16 + quad * 4 + reg;
        float v = acc1[mi][reg] + b1v;
        v = 0.5f * v * (1.f + erff(v * 0.70710678118654752f));
        *(bf16*)(H + r * 128 + ((2 * hcol) ^ ((r & 7) << 4))) =
            __float2bfloat16(v);
      }
    __syncthreads();  // Hs[nc&1] ready; also guards WAR on Hs[(nc-1)&1]

    // GEMM2 partial: out 64x192 += H(64x64) * W2chunk^T, wave tile 64x48.
#pragma unroll
    for (int ks = 0; ks < 2; ks++) {
      const int kb = ks * 64 + quad * 16;
      short8 ha[4];
#pragma unroll
      for (int mi = 0; mi < 4; mi++)
        ha[mi] = lds_frag128(H, mi * 16 + lanelo, kb);
#pragma unroll
      for (int ni = 0; ni < 3; ni++) {
        short8 bv = *(const short8*)((const char*)w2t +
                                     (long)(ocol0 + ni * 16 + lanelo) * 1536 +
                                     nc * 128 + kb);
#pragma unroll
        for (int mi = 0; mi < 4; mi++)
          acc2[mi][ni] = mfma16(ha[mi], bv, acc2[mi][ni]);
      }
    }
  }

  // epilogue: + bias2 + residual, fp32 in-place
#pragma unroll
  for (int mi = 0; mi < 4; mi++)
#pragma unroll
    for (int ni = 0; ni < 3; ni++) {
      const int c = ocol0 + ni * 16 + lanelo;
      const float b2v = b2[c];
#pragma unroll
      for (int reg = 0; reg < 4; reg++) {
        const long g = (row0 + mi * 16 + quad * 4 + reg) * 192 + c;
        xres[g] = acc2[mi][ni][reg] + b2v + xres[g];
      }
    }
}

// ---------------------------------------------------------------------------
extern "C" void kernel_launch(void* const* d_in, const int* in_sizes, int n_in,
                              void* d_out, int out_size, void* d_ws, size_t ws_size,
                              hipStream_t stream) {
  const float* x     = (const float*)d_in[0];
  const float* n1w   = (const float*)d_in[1];
  const float* n1b   = (const float*)d_in[2];
  const float* qkvw  = (const float*)d_in[3];
  const float* qkvb  = (const float*)d_in[4];
  const float* rpb   = (const float*)d_in[5];
  const float* projw = (const float*)d_in[6];
  const float* projb = (const float*)d_in[7];
  const float* n2w   = (const float*)d_in[8];
  const float* n2b   = (const float*)d_in[9];
  const float* fc1w  = (const float*)d_in[10];
  const float* fc1b  = (const float*)d_in[11];
  const float* fc2w  = (const float*)d_in[12];
  const float* fc2b  = (const float*)d_in[13];
  float* outf = (float*)d_out;  // residual buffer, then final output

  // workspace layout:
  //   B0 [0,        77070336)  xw bf16 (200704x192)
  //   B1 [77070336, 154140672) attC bf16 (200704x192)
  //   W  [154140672, ...)      bf16 weights (~0.9 MB)
  char* ws = (char*)d_ws;
  bf16* xw      = (bf16*)(ws + 0);
  bf16* attC    = (bf16*)(ws + 77070336LL);
  bf16* wt_qkv  = (bf16*)(ws + 154140672LL);                  // 576x192
  bf16* wt_proj = (bf16*)(ws + 154140672LL + 221184LL);       // 192x192
  bf16* wt_fc1  = (bf16*)(ws + 154140672LL + 294912LL);       // 768x192
  bf16* wt_fc2  = (bf16*)(ws + 154140672LL + 589824LL);       // 192x768

  // transpose + cast weights to bf16 (N x K)
  k_wt<<<dim3((192 * 576 + 255) / 256), 256, 0, stream>>>(qkvw, wt_qkv, 192, 576);
  k_wt<<<dim3((192 * 192 + 255) / 256), 256, 0, stream>>>(projw, wt_proj, 192, 192);
  k_wt<<<dim3((192 * 768 + 255) / 256), 256, 0, stream>>>(fc1w, wt_fc1, 192, 768);
  k_wt<<<dim3((768 * 192 + 255) / 256), 256, 0, stream>>>(fc2w, wt_fc2, 768, 192);

  // LN1 + shift + window partition -> xw (window-order rows, full tensor)
  k_ln<true><<<dim3(50176), 256, 0, stream>>>(x, n1w, n1b, xw);

  // QKV + windowed MHA, one wave per (window, head), zero barriers
  k_attn2<<<dim3(6144), 256, 0, stream>>>(xw, wt_qkv, qkvb, rpb, attC);

  // proj + residual + window-reverse scatter (full tensor, one launch)
  k_gemm<2><<<dim3(3136, 3), 256, 0, stream>>>(attC, wt_proj, projb, nullptr,
                                               outf, x, 192, 192, 0);

  // fused LN2 + MLP + residual, in-place on d_out (64 rows per block)
  k_mlp<<<dim3(3136), 256, 0, stream>>>(outf, n2w, n2b, wt_fc1, fc1b,
                                        wt_fc2, fc2b);
}

// Round 11
// 988.398 us; speedup vs baseline: 1.0757x; 1.0047x over previous
//
#include <hip/hip_runtime.h>
#include <hip/hip_bf16.h>

typedef __hip_bfloat16 bf16;
typedef __attribute__((ext_vector_type(8))) short short8;
typedef __attribute__((ext_vector_type(4))) short short4v;
typedef __attribute__((ext_vector_type(4))) float floatx4;

__device__ __forceinline__ floatx4 mfma16(short8 a, short8 b, floatx4 c) {
  return __builtin_amdgcn_mfma_f32_16x16x32_bf16(a, b, c, 0, 0, 0);
}

__device__ __forceinline__ float wave_sum(float v) {
#pragma unroll
  for (int off = 1; off < 64; off <<= 1) v += __shfl_xor(v, off);
  return v;
}

// async global -> LDS, 16 bytes per lane
__device__ __forceinline__ void gload16(const void* g, void* l) {
  __builtin_amdgcn_global_load_lds(
      (const __attribute__((address_space(1))) unsigned int*)g,
      (__attribute__((address_space(3))) unsigned int*)l, 16, 0, 0);
}

// swizzled LDS fragment read: row stride 384B, XOR bits[6:4] with row&7
__device__ __forceinline__ short8 lds_frag(const char* base, int row, int kb) {
  return *(const short8*)(base + row * 384 + (kb ^ ((row & 7) << 4)));
}
// same, row stride 128B
__device__ __forceinline__ short8 lds_frag128(const char* base, int row, int kb) {
  return *(const short8*)(base + row * 128 + (kb ^ ((row & 7) << 4)));
}

// ---------------------------------------------------------------------------
// Weight transpose + bf16 cast: w (K x N) fp32 -> wt (N x K) bf16
// ---------------------------------------------------------------------------
__global__ __launch_bounds__(256) void k_wt(const float* __restrict__ w,
                                            bf16* __restrict__ wt, int K, int N) {
  int id = blockIdx.x * 256 + threadIdx.x;
  if (id < K * N) {
    int n = id / K;
    int k = id - n * K;
    wt[id] = __float2bfloat16(w[(long)k * N + n]);
  }
}

// ---------------------------------------------------------------------------
// Masked bias table: Btab[cls][head][i][j] = rpb bias + shift-mask, fp32.
// cls = (row-boundary window? 2:0) + (col-boundary window? 1:0).
// j >= 49 -> -1e30 (pad col); i clamped to 48 (pad row, never stored).
// Values bit-identical to the in-kernel computation it replaces.
// ---------------------------------------------------------------------------
__global__ __launch_bounds__(256) void k_bias(const float* __restrict__ rpb,
                                              float* __restrict__ Btab) {
  const int bh = blockIdx.x;          // cls*6 + head
  const int cls = bh / 6, head = bh - cls * 6;
  const bool rb = (cls & 2) != 0, cb = (cls & 1) != 0;
  for (int idx = threadIdx.x; idx < 4096; idx += 256) {
    int i = idx >> 6, j = idx & 63;
    float v;
    if (j >= 49) {
      v = -1e30f;
    } else {
      int ie = (i > 48) ? 48 : i;
      int ti = ie / 7, tj = ie - ti * 7;
      int cti = j / 7, ctj = j - cti * 7;
      int ridx = (ti - cti + 6) * 13 + (tj - ctj + 6);
      v = rpb[ridx * 6 + head];
      int rlab = (rb ? (ti < 4 ? 1 : 2) : 0) * 3 + (cb ? (tj < 4 ? 1 : 2) : 0);
      int clab = (rb ? (cti < 4 ? 1 : 2) : 0) * 3 + (cb ? (ctj < 4 ? 1 : 2) : 0);
      if (rlab != clab) v -= 100.f;
    }
    Btab[(long)bh * 4096 + i * 64 + j] = v;
  }
}

// ---------------------------------------------------------------------------
// LayerNorm over C=192. One wave per row. GATHER=true applies cyclic shift
// (-3,-3) + window partition: output row order = (b, wi, wj, ti, tj).
// ---------------------------------------------------------------------------
template <bool GATHER>
__global__ __launch_bounds__(256) void k_ln(const float* __restrict__ xin,
                                            const float* __restrict__ w,
                                            const float* __restrict__ b,
                                            bf16* __restrict__ out) {
  const int lane = threadIdx.x & 63;
  const long row = (long)blockIdx.x * 4 + (threadIdx.x >> 6);
  long srow;
  if (GATHER) {
    int win = (int)(row / 49);
    int token = (int)(row - (long)win * 49);
    int bimg = win >> 6, wi = (win & 63) >> 3, wj = win & 7;
    int ti = token / 7, tj = token - ti * 7;
    int h = wi * 7 + ti + 3; if (h >= 56) h -= 56;
    int ww = wj * 7 + tj + 3; if (ww >= 56) ww -= 56;
    srow = (long)bimg * 3136 + h * 56 + ww;
  } else {
    srow = row;
  }
  const float* src = xin + srow * 192;
  float v0 = src[lane], v1 = src[lane + 64], v2 = src[lane + 128];
  float mu = wave_sum(v0 + v1 + v2) * (1.f / 192.f);
  float d0 = v0 - mu, d1 = v1 - mu, d2 = v2 - mu;
  float var = wave_sum(d0 * d0 + d1 * d1 + d2 * d2) * (1.f / 192.f);
  float rs = rsqrtf(var + 1e-5f);
  bf16* dst = out + row * 192;
  dst[lane]       = __float2bfloat16(d0 * rs * w[lane] + b[lane]);
  dst[lane + 64]  = __float2bfloat16(d1 * rs * w[lane + 64] + b[lane + 64]);
  dst[lane + 128] = __float2bfloat16(d2 * rs * w[lane + 128] + b[lane + 128]);
}

// ---------------------------------------------------------------------------
// GEMM: C = A (M x K, bf16 rm) * Bt^T (Bt is N x K bf16) + bias
// 64x64 block tile, 4 waves of 32x32, MFMA 16x16x32 bf16.
// EPI 2: window-reverse scatter + shortcut add, fp32   [proj -> d_out]
// ---------------------------------------------------------------------------
template <int EPI>
__global__ __launch_bounds__(256, 3) void k_gemm(const bf16* __restrict__ A,
                                                 const bf16* __restrict__ Bt,
                                                 const float* __restrict__ bias,
                                                 bf16* __restrict__ Cbf,
                                                 float* __restrict__ Cfp,
                                                 const float* __restrict__ res,
                                                 int Ncols, int K, long row0) {
  __shared__ __align__(16) char As[64 * 384];  // 24576 B: 64 rows x 192 bf16
  __shared__ __align__(16) char Bs[64 * 384];
  const int t = threadIdx.x;
  const int lane = t & 63, wid = t >> 6;
  const int lanelo = lane & 15, quad = lane >> 4;
  const long m0 = (long)blockIdx.x * 64;
  const int n0 = blockIdx.y * 64;
  const int wm = (wid >> 1) * 32, wn = (wid & 1) * 32;

  floatx4 acc[2][2];
#pragma unroll
  for (int i = 0; i < 2; i++)
#pragma unroll
    for (int j = 0; j < 2; j++) acc[i][j] = (floatx4){0.f, 0.f, 0.f, 0.f};

  const char* Ab = (const char*)(A + m0 * (long)K);
  const char* Bb = (const char*)(Bt + (long)n0 * K);
  const int ldab = 2 * K;  // bytes per source row

  for (int k0b = 0; k0b < 2 * K; k0b += 384) {
    __syncthreads();
#pragma unroll
    for (int i = 0; i < 6; i++) {
      int c = i * 256 + t;          // chunk index
      int r = c / 24;               // row in tile (24 chunks per 384B row)
      int j = c - r * 24;
      int be = (j * 16) ^ ((r & 7) << 4);
      gload16(Ab + (long)r * ldab + k0b + be, As + c * 16);
      gload16(Bb + (long)r * ldab + k0b + be, Bs + c * 16);
    }
    __syncthreads();  // drains vmcnt(0) -> panels resident

#pragma unroll
    for (int kk = 0; kk < 6; kk++) {
      const int kb = kk * 64 + quad * 16;
      short8 a0 = lds_frag(As, wm + lanelo, kb);
      short8 a1 = lds_frag(As, wm + 16 + lanelo, kb);
      short8 b0 = lds_frag(Bs, wn + lanelo, kb);
      short8 b1 = lds_frag(Bs, wn + 16 + lanelo, kb);
      acc[0][0] = mfma16(a0, b0, acc[0][0]);
      acc[0][1] = mfma16(a0, b1, acc[0][1]);
      acc[1][0] = mfma16(a1, b0, acc[1][0]);
      acc[1][1] = mfma16(a1, b1, acc[1][1]);
    }
  }

#pragma unroll
  for (int mi = 0; mi < 2; mi++) {
#pragma unroll
    for (int reg = 0; reg < 4; reg++) {
      const long r = m0 + wm + mi * 16 + quad * 4 + reg;
      long orow = r;
      if (EPI == 2) {
        const long rg = row0 + r;
        int win = (int)(rg / 49);
        int token = (int)(rg - (long)win * 49);
        int bimg = win >> 6, wi = (win & 63) >> 3, wj = win & 7;
        int ti = token / 7, tj = token - ti * 7;
        int h = wi * 7 + ti + 3; if (h >= 56) h -= 56;
        int ww = wj * 7 + tj + 3; if (ww >= 56) ww -= 56;
        orow = (long)bimg * 3136 + h * 56 + ww;
      }
#pragma unroll
      for (int ni = 0; ni < 2; ni++) {
        const int c = n0 + wn + ni * 16 + lanelo;
        float v = acc[mi][ni][reg] + bias[c];
        if (EPI == 0) {
          Cbf[r * Ncols + c] = __float2bfloat16(v);
        } else if (EPI == 1) {
          v = 0.5f * v * (1.f + erff(v * 0.70710678118654752f));
          Cbf[r * Ncols + c] = __float2bfloat16(v);
        } else if (EPI == 2) {
          Cfp[orow * 192 + c] = v + res[orow * 192 + c];
        } else {
          Cfp[r * 192 + c] = v + res[r * 192 + c];
        }
      }
    }
  }
}

// ---------------------------------------------------------------------------
// QKV + windowed attention, one WAVE per (window, head), ZERO barriers.
// v2: QKV split into QK-pass (acc 4x4) + V-pass (acc 4x2) to cut the register
// peak (was aq[4][6]=96 live); A-fragments re-read in pass 2 are L1-hot.
// Softmax uses the precomputed masked bias table Btab (no rpb gather, no
// label math). Values bit-identical to v1.
// LDS: 4 x 14848 B = 59392 -> 2 blocks/CU.
// ---------------------------------------------------------------------------
__global__ __launch_bounds__(256, 2) void k_attn2(const bf16* __restrict__ xw,
                                                  const bf16* __restrict__ wq,
                                                  const float* __restrict__ qkvb,
                                                  const float* __restrict__ Btab,
                                                  bf16* __restrict__ attC) {
  __shared__ __align__(16) bf16 smem[4 * 7424];
  const int t = threadIdx.x, lane = t & 63, wid = t >> 6;
  const int lanelo = lane & 15, quad = lane >> 4;
  const int unit = blockIdx.x * 4 + wid;
  const int win = unit / 6, head = unit - win * 6;
  bf16* Qs = smem + wid * 7424;  // 64 rows, stride 40
  bf16* Ks = Qs + 2560;          // 64 rows, stride 40
  bf16* Vt = Qs + 5120;          // 32 rows (d), stride 72, cols = token
  bf16* Ps = Qs;                 // 64 rows, stride 72 (overlays Q/K)
  const long rowbase = (long)win * 49;

  const int w_in = win & 63;
  const int cls = (((w_in >> 3) == 7) ? 2 : 0) + (((w_in & 7) == 7) ? 1 : 0);
  const float* Bt = Btab + (long)(cls * 6 + head) * 4096;

  const float scale = 0.17677669529663687f;  // 1/sqrt(32)

  // ---- pass 1: Q,K (64 rows x 64 cols), K=192 ----
  {
    floatx4 aq[4][4];
#pragma unroll
    for (int mi = 0; mi < 4; mi++)
#pragma unroll
      for (int ni = 0; ni < 4; ni++) aq[mi][ni] = (floatx4){0.f, 0.f, 0.f, 0.f};
#pragma unroll
    for (int kk = 0; kk < 6; kk++) {
      const int kb = kk * 64 + quad * 16;
      short8 af[4];
#pragma unroll
      for (int mi = 0; mi < 4; mi++)
        af[mi] = *(const short8*)((const char*)xw +
                                  (rowbase + mi * 16 + lanelo) * 384 + kb);
#pragma unroll
      for (int ni = 0; ni < 4; ni++) {
        const int wrow = (ni >> 1) * 192 + head * 32 + (ni & 1) * 16 + lanelo;
        short8 bf = *(const short8*)((const char*)wq + (long)wrow * 384 + kb);
#pragma unroll
        for (int mi = 0; mi < 4; mi++) aq[mi][ni] = mfma16(af[mi], bf, aq[mi][ni]);
      }
    }
#pragma unroll
    for (int ni = 0; ni < 4; ni++) {
      const int p = ni >> 1;
      const int d = (ni & 1) * 16 + lanelo;
      const float bb = qkvb[p * 192 + head * 32 + d];
      bf16* dst = (p == 0) ? Qs : Ks;
#pragma unroll
      for (int mi = 0; mi < 4; mi++)
#pragma unroll
        for (int reg = 0; reg < 4; reg++) {
          int tok = mi * 16 + quad * 4 + reg;
          dst[tok * 40 + d] = __float2bfloat16(aq[mi][ni][reg] + bb);
        }
    }
  }

  // ---- pass 2: V (64 rows x 32 cols), K=192; A-frags L1-hot ----
  {
    floatx4 av[4][2];
#pragma unroll
    for (int mi = 0; mi < 4; mi++)
#pragma unroll
      for (int ni = 0; ni < 2; ni++) av[mi][ni] = (floatx4){0.f, 0.f, 0.f, 0.f};
#pragma unroll
    for (int kk = 0; kk < 6; kk++) {
      const int kb = kk * 64 + quad * 16;
      short8 af[4];
#pragma unroll
      for (int mi = 0; mi < 4; mi++)
        af[mi] = *(const short8*)((const char*)xw +
                                  (rowbase + mi * 16 + lanelo) * 384 + kb);
#pragma unroll
      for (int ni = 0; ni < 2; ni++) {
        const int wrow = 384 + head * 32 + ni * 16 + lanelo;
        short8 bf = *(const short8*)((const char*)wq + (long)wrow * 384 + kb);
#pragma unroll
        for (int mi = 0; mi < 4; mi++) av[mi][ni] = mfma16(af[mi], bf, av[mi][ni]);
      }
    }
#pragma unroll
    for (int ni = 0; ni < 2; ni++) {
      const int d = ni * 16 + lanelo;
      const float bb = qkvb[384 + head * 32 + d];
#pragma unroll
      for (int mi = 0; mi < 4; mi++) {
        union { short4v s; bf16 hh[4]; } pv;
#pragma unroll
        for (int reg = 0; reg < 4; reg++)
          pv.hh[reg] = __float2bfloat16(av[mi][ni][reg] + bb);
        *(short4v*)(&Vt[d * 72 + mi * 16 + quad * 4]) = pv.s;
      }
    }
  }
  // wave-private LDS: in-wave lgkmcnt ordering suffices, no barrier

  // ---- S = Q K^T : 64x64 + softmax (bias from Btab) ----
  float rinv[16];
  {
    floatx4 aS[4][4];
#pragma unroll
    for (int mi = 0; mi < 4; mi++) {
      short8 aqf = *(const short8*)(&Qs[(mi * 16 + lanelo) * 40 + quad * 8]);
#pragma unroll
      for (int ni = 0; ni < 4; ni++) {
        short8 bk = *(const short8*)(&Ks[(ni * 16 + lanelo) * 40 + quad * 8]);
        aS[mi][ni] = mfma16(aqf, bk, (floatx4){0.f, 0.f, 0.f, 0.f});
      }
    }
#pragma unroll
    for (int mi = 0; mi < 4; mi++) {
#pragma unroll
      for (int reg = 0; reg < 4; reg++) {
        const int i = mi * 16 + quad * 4 + reg;
        const float* bp = Bt + i * 64;
        float sv[4];
        float mx = -1e30f;
#pragma unroll
        for (int ni = 0; ni < 4; ni++) {
          float s = aS[mi][ni][reg] * scale + bp[ni * 16 + lanelo];
          sv[ni] = s;
          mx = fmaxf(mx, s);
        }
        mx = fmaxf(mx, __shfl_xor(mx, 1));
        mx = fmaxf(mx, __shfl_xor(mx, 2));
        mx = fmaxf(mx, __shfl_xor(mx, 4));
        mx = fmaxf(mx, __shfl_xor(mx, 8));
        float sum = 0.f;
#pragma unroll
        for (int ni = 0; ni < 4; ni++) {
          float p = __expf(sv[ni] - mx);
          sv[ni] = p;
          sum += p;
        }
        sum += __shfl_xor(sum, 1);
        sum += __shfl_xor(sum, 2);
        sum += __shfl_xor(sum, 4);
        sum += __shfl_xor(sum, 8);
        rinv[mi * 4 + reg] = 1.f / sum;
#pragma unroll
        for (int ni = 0; ni < 4; ni++) aS[mi][ni][reg] = sv[ni];
      }
    }
    // P -> LDS (overlays Q/K; same-wave DS ops are ordered)
#pragma unroll
    for (int mi = 0; mi < 4; mi++)
#pragma unroll
      for (int ni = 0; ni < 4; ni++)
#pragma unroll
        for (int reg = 0; reg < 4; reg++)
          Ps[(mi * 16 + quad * 4 + reg) * 72 + ni * 16 + lanelo] =
              __float2bfloat16(aS[mi][ni][reg]);
  }

  // ---- O = P * V : 64x32, K=64 ----
  floatx4 aO[4][2];
#pragma unroll
  for (int mi = 0; mi < 4; mi++)
#pragma unroll
    for (int ni = 0; ni < 2; ni++) aO[mi][ni] = (floatx4){0.f, 0.f, 0.f, 0.f};
#pragma unroll
  for (int ks = 0; ks < 2; ks++) {
#pragma unroll
    for (int mi = 0; mi < 4; mi++) {
      short8 ap = *(const short8*)(&Ps[(mi * 16 + lanelo) * 72 + ks * 32 + quad * 8]);
#pragma unroll
      for (int ni = 0; ni < 2; ni++) {
        short8 bv = *(const short8*)(&Vt[(ni * 16 + lanelo) * 72 + ks * 32 + quad * 8]);
        aO[mi][ni] = mfma16(ap, bv, aO[mi][ni]);
      }
    }
  }

  // ---- store O band (this head's 32 cols) to attC ----
#pragma unroll
  for (int mi = 0; mi < 4; mi++)
#pragma unroll
    for (int reg = 0; reg < 4; reg++) {
      int i = mi * 16 + quad * 4 + reg;
      if (i < 49) {
        float rv = rinv[mi * 4 + reg];
#pragma unroll
        for (int ni = 0; ni < 2; ni++) {
          int d = ni * 16 + lanelo;
          attC[(rowbase + i) * 192 + head * 32 + d] =
              __float2bfloat16(aO[mi][ni][reg] * rv);
        }
      }
    }
}

// ---------------------------------------------------------------------------
// Fused LN2 + fc1 + GELU + fc2 + residual, in-place on the fp32 tensor.
// 64 rows/block, 256 threads, 3136 blocks, 4 blocks/CU (LDS 40KB).
// Direct-global weight fragments; Hs double-buffered; 1 barrier/chunk.
// ---------------------------------------------------------------------------
__global__ __launch_bounds__(256, 4) void k_mlp(float* xres,
                                                const float* __restrict__ lw,
                                                const float* __restrict__ lb,
                                                const bf16* __restrict__ w1t,
                                                const float* __restrict__ b1,
                                                const bf16* __restrict__ w2t,
                                                const float* __restrict__ b2) {
  __shared__ __align__(16) char As[64 * 384];     // LN'd rows, K=192 (swizzled)
  __shared__ __align__(16) char Hs[2][64 * 128];  // gelu(hid) chunk dbuf
  const int t = threadIdx.x, lane = t & 63, wid = t >> 6;
  const int lanelo = lane & 15, quad = lane >> 4;
  const long row0 = (long)blockIdx.x * 64;

  // ---- LN2 -> As (bf16, row-XOR swizzled); 16 rows per wave ----
  for (int i = 0; i < 16; i++) {
    int r = wid * 16 + i;
    const float* src = xres + (row0 + r) * 192;
    float v0 = src[lane], v1 = src[lane + 64], v2 = src[lane + 128];
    float mu = wave_sum(v0 + v1 + v2) * (1.f / 192.f);
    float d0 = v0 - mu, d1 = v1 - mu, d2 = v2 - mu;
    float var = wave_sum(d0 * d0 + d1 * d1 + d2 * d2) * (1.f / 192.f);
    float rs = rsqrtf(var + 1e-5f);
    int sw = (r & 7) << 4;
    *(bf16*)(As + r * 384 + ((2 * lane) ^ sw)) =
        __float2bfloat16(d0 * rs * lw[lane] + lb[lane]);
    *(bf16*)(As + r * 384 + ((128 + 2 * lane) ^ sw)) =
        __float2bfloat16(d1 * rs * lw[lane + 64] + lb[lane + 64]);
    *(bf16*)(As + r * 384 + ((256 + 2 * lane) ^ sw)) =
        __float2bfloat16(d2 * rs * lw[lane + 128] + lb[lane + 128]);
  }

  floatx4 acc2[4][3];
#pragma unroll
  for (int mi = 0; mi < 4; mi++)
#pragma unroll
    for (int ni = 0; ni < 3; ni++) acc2[mi][ni] = (floatx4){0.f, 0.f, 0.f, 0.f};

  __syncthreads();  // As ready

  const int hcol = wid * 16 + lanelo;          // GEMM1 col owned by this lane
  const int ocol0 = wid * 48;                  // GEMM2 col base for this wave

  for (int nc = 0; nc < 12; nc++) {
    // GEMM1: hid chunk cols [nc*64 + wid*16, +16), 64 rows, K=192.
    const char* w1p = (const char*)w1t + (long)(nc * 64 + hcol) * 384;
    floatx4 acc1[4];
#pragma unroll
    for (int mi = 0; mi < 4; mi++) acc1[mi] = (floatx4){0.f, 0.f, 0.f, 0.f};
#pragma unroll
    for (int kk = 0; kk < 6; kk++) {
      const int kb = kk * 64 + quad * 16;
      short8 bf = *(const short8*)(w1p + kb);
#pragma unroll
      for (int mi = 0; mi < 4; mi++) {
        short8 af = lds_frag(As, mi * 16 + lanelo, kb);
        acc1[mi] = mfma16(af, bf, acc1[mi]);
      }
    }

    // bias + exact GELU -> Hs[nc&1] (bf16, swizzled)
    char* H = Hs[nc & 1];
    const float b1v = b1[nc * 64 + hcol];
#pragma unroll
    for (int mi = 0; mi < 4; mi++)
#pragma unroll
      for (int reg = 0; reg < 4; reg++) {
        int r = mi * 16 + quad * 4 + reg;
        float v = acc1[mi][reg] + b1v;
        v = 0.5f * v * (1.f + erff(v * 0.70710678118654752f));
        *(bf16*)(H + r * 128 + ((2 * hcol) ^ ((r & 7) << 4))) =
            __float2bfloat16(v);
      }
    __syncthreads();  // Hs[nc&1] ready; also guards WAR on Hs[(nc-1)&1]

    // GEMM2 partial: out 64x192 += H(64x64) * W2chunk^T, wave tile 64x48.
#pragma unroll
    for (int ks = 0; ks < 2; ks++) {
      const int kb = ks * 64 + quad * 16;
      short8 ha[4];
#pragma unroll
      for (int mi = 0; mi < 4; mi++)
        ha[mi] = lds_frag128(H, mi * 16 + lanelo, kb);
#pragma unroll
      for (int ni = 0; ni < 3; ni++) {
        short8 bv = *(const short8*)((const char*)w2t +
                                     (long)(ocol0 + ni * 16 + lanelo) * 1536 +
                                     nc * 128 + kb);
#pragma unroll
        for (int mi = 0; mi < 4; mi++)
          acc2[mi][ni] = mfma16(ha[mi], bv, acc2[mi][ni]);
      }
    }
  }

  // epilogue: + bias2 + residual, fp32 in-place
#pragma unroll
  for (int mi = 0; mi < 4; mi++)
#pragma unroll
    for (int ni = 0; ni < 3; ni++) {
      const int c = ocol0 + ni * 16 + lanelo;
      const float b2v = b2[c];
#pragma unroll
      for (int reg = 0; reg < 4; reg++) {
        const long g = (row0 + mi * 16 + quad * 4 + reg) * 192 + c;
        xres[g] = acc2[mi][ni][reg] + b2v + xres[g];
      }
    }
}

// ---------------------------------------------------------------------------
extern "C" void kernel_launch(void* const* d_in, const int* in_sizes, int n_in,
                              void* d_out, int out_size, void* d_ws, size_t ws_size,
                              hipStream_t stream) {
  const float* x     = (const float*)d_in[0];
  const float* n1w   = (const float*)d_in[1];
  const float* n1b   = (const float*)d_in[2];
  const float* qkvw  = (const float*)d_in[3];
  const float* qkvb  = (const float*)d_in[4];
  const float* rpb   = (const float*)d_in[5];
  const float* projw = (const float*)d_in[6];
  const float* projb = (const float*)d_in[7];
  const float* n2w   = (const float*)d_in[8];
  const float* n2b   = (const float*)d_in[9];
  const float* fc1w  = (const float*)d_in[10];
  const float* fc1b  = (const float*)d_in[11];
  const float* fc2w  = (const float*)d_in[12];
  const float* fc2b  = (const float*)d_in[13];
  float* outf = (float*)d_out;  // scratch (Btab) -> residual buffer -> output

  // workspace layout:
  //   B0 [0,        77070336)  xw bf16 (200704x192)
  //   B1 [77070336, 154140672) attC bf16 (200704x192)
  //   W  [154140672, ...)      bf16 weights (~0.9 MB)
  // Btab (4x6x64x64 fp32, 393 KB) lives in d_out scratch: written by k_bias,
  // read by k_attn2, then d_out is overwritten by k_gemm<2>.
  char* ws = (char*)d_ws;
  bf16* xw      = (bf16*)(ws + 0);
  bf16* attC    = (bf16*)(ws + 77070336LL);
  bf16* wt_qkv  = (bf16*)(ws + 154140672LL);                  // 576x192
  bf16* wt_proj = (bf16*)(ws + 154140672LL + 221184LL);       // 192x192
  bf16* wt_fc1  = (bf16*)(ws + 154140672LL + 294912LL);       // 768x192
  bf16* wt_fc2  = (bf16*)(ws + 154140672LL + 589824LL);       // 192x768
  float* Btab   = (float*)d_out;

  // transpose + cast weights to bf16 (N x K)
  k_wt<<<dim3((192 * 576 + 255) / 256), 256, 0, stream>>>(qkvw, wt_qkv, 192, 576);
  k_wt<<<dim3((192 * 192 + 255) / 256), 256, 0, stream>>>(projw, wt_proj, 192, 192);
  k_wt<<<dim3((192 * 768 + 255) / 256), 256, 0, stream>>>(fc1w, wt_fc1, 192, 768);
  k_wt<<<dim3((768 * 192 + 255) / 256), 256, 0, stream>>>(fc2w, wt_fc2, 768, 192);

  // masked bias table (4 window classes x 6 heads x 64 x 64)
  k_bias<<<dim3(24), 256, 0, stream>>>(rpb, Btab);

  // LN1 + shift + window partition -> xw (window-order rows, full tensor)
  k_ln<true><<<dim3(50176), 256, 0, stream>>>(x, n1w, n1b, xw);

  // QKV + windowed MHA, one wave per (window, head), zero barriers
  k_attn2<<<dim3(6144), 256, 0, stream>>>(xw, wt_qkv, qkvb, Btab, attC);

  // proj + residual + window-reverse scatter (full tensor, one launch)
  k_gemm<2><<<dim3(3136, 3), 256, 0, stream>>>(attC, wt_proj, projb, nullptr,
                                               outf, x, 192, 192, 0);

  // fused LN2 + MLP + residual, in-place on d_out (64 rows per block)
  k_mlp<<<dim3(3136), 256, 0, stream>>>(outf, n2w, n2b, wt_fc1, fc1b,
                                        wt_fc2, fc2b);
}